// Round 6
// baseline (1192.429 us; speedup 1.0000x reference)
//
#include <hip/hip_runtime.h>
#include <hip/hip_fp16.h>

// GCN 3-layer, PUSH-mode layers (R19).
// Build: count1/scan -> region bases; scatter1 (in-LDS counting sort, R16)
// sorts edges by dst-superbucket (4096 nodes) into pk1; buildpush re-sorts
// each region by src-superbucket (128 buckets) into pk2 (same 31-bit packing
// (dst&4095)|(src<<12)), computes degrees -> dinv + z1 (half2), and writes
// tile boundaries tb[reg][srcSB].
// Layers (R19): block = (dst-region, src-quarter) [492 blocks]; fp32 acc for
// 4096 dst nodes in LDS; edges walked in src-window order so z-table gathers
// hit a rolling 16-32KB L1-resident window (R18 proved the wall is per-XCD
// L2 random-request rate ~0.2 line/cyc/CU: pull-gather sent every request to
// L2; push+tiling keeps them in L1). Per edge: 2-4 LDS atomicAdd(f32).
// Partials (4/region) merged in thread-per-node finalize with self-term +
// dinv + W/tanh epilogue. No csr/rowptr; no EB_CAP. partial aliases pk1
// (dead after buildpush).
// R13: z2 4xfp16 (8B). R14: z1/z3 half2 (4B). fp16 budget: absmax ~2.4e-4.
// Math per layer (input u): z = u*dinv; s_i = sum_{e:dst=i} z[src_e];
//   out_i = (dinv_i*(s_i + z_i)) @ W + b   (self-loop folds into s+z).

#define TPB 256
#define T_TILE 16384
#define SBB 12           // superbucket = 4096 nodes
#define NSB_MAX 128

// ---------------- pass 0: per-tile superbucket histogram ----------------

__global__ void __launch_bounds__(512)
count1(const int* __restrict__ dst, int* __restrict__ cnt1, int ntB, int E, int SB) {
    __shared__ int hist[NSB_MAX];
    int blk = blockIdx.x, tid = threadIdx.x;
    if (tid < SB) hist[tid] = 0;
    __syncthreads();
    int base = blk * T_TILE;
    #pragma unroll 8
    for (int it = 0; it < T_TILE / 512; ++it) {
        int e = base + it * 512 + tid;
        if (e < E) atomicAdd(&hist[((unsigned)dst[e]) >> SBB], 1);
    }
    __syncthreads();
    if (tid < SB) cnt1[(size_t)tid * ntB + blk] = hist[tid];
}

// ---- 3-kernel exclusive scan over data[len] (in-place), 1024 elems/block ----
__global__ void scan_k1(const int* __restrict__ data, int* __restrict__ bsum, int len) {
    __shared__ int lds[TPB];
    int b = blockIdx.x, t = threadIdx.x;
    int base = b * 1024 + t * 4;
    int s = 0;
    #pragma unroll
    for (int j = 0; j < 4; ++j) { int i = base + j; if (i < len) s += data[i]; }
    lds[t] = s; __syncthreads();
    for (int off = 128; off > 0; off >>= 1) {
        if (t < off) lds[t] += lds[t + off];
        __syncthreads();
    }
    if (t == 0) bsum[b] = lds[0];
}

__global__ void scan_k2(int* __restrict__ bsum, int NB) {
    __shared__ int lds[1024];
    int t = threadIdx.x;
    int v = (t < NB) ? bsum[t] : 0;
    lds[t] = v; __syncthreads();
    for (int off = 1; off < 1024; off <<= 1) {
        int add = (t >= off) ? lds[t - off] : 0;
        __syncthreads();
        lds[t] += add;
        __syncthreads();
    }
    if (t < NB) bsum[t] = lds[t] - v;  // exclusive
}

__global__ void scan_k3(int* __restrict__ data, const int* __restrict__ bsum, int len) {
    __shared__ int lds[TPB];
    int b = blockIdx.x, t = threadIdx.x;
    int base = b * 1024 + t * 4;
    int v[4]; int s = 0;
    #pragma unroll
    for (int j = 0; j < 4; ++j) { int i = base + j; v[j] = (i < len) ? data[i] : 0; s += v[j]; }
    int orig = s;
    lds[t] = s; __syncthreads();
    for (int off = 1; off < 256; off <<= 1) {
        int add = (t >= off) ? lds[t - off] : 0;
        __syncthreads();
        lds[t] += add;
        __syncthreads();
    }
    int run = bsum[b] + lds[t] - orig;
    #pragma unroll
    for (int j = 0; j < 4; ++j) {
        int i = base + j;
        if (i < len) { data[i] = run; run += v[j]; }
    }
}

__global__ void bases_fix(const int* __restrict__ cnt1, int ntB, int SB,
                          int* __restrict__ bases1, int E) {
    int t = threadIdx.x;
    if (t < SB) bases1[t] = cnt1[(size_t)t * ntB];
    if (t == 0) bases1[SB] = E;
}

// ---- pass 1: in-LDS counting-sort scatter (coalesced write-back, R16) ----
__global__ void __launch_bounds__(512)
scatter1(const int* __restrict__ dst, const int* __restrict__ src,
         const int* __restrict__ cnt1, unsigned* __restrict__ pk1,
         int ntB, int E, int SB) {
    __shared__ unsigned lpk[T_TILE];   // 64KB staged packed values
    __shared__ int lhist[NSB_MAX];
    __shared__ int lexcl[NSB_MAX];
    __shared__ int lcur[NSB_MAX];
    __shared__ int basec[NSB_MAX];
    int blk = blockIdx.x, tid = threadIdx.x;
    if (tid < NSB_MAX) lhist[tid] = 0;
    if (tid < SB) basec[tid] = cnt1[(size_t)tid * ntB + blk];
    __syncthreads();
    int base = blk * T_TILE;
    #pragma unroll 8
    for (int it = 0; it < T_TILE / 512; ++it) {
        int e = base + it * 512 + tid;
        if (e < E) atomicAdd(&lhist[((unsigned)dst[e]) >> SBB], 1);
    }
    __syncthreads();
    int hv = (tid < NSB_MAX) ? lhist[tid] : 0;
    if (tid < NSB_MAX) lexcl[tid] = hv;
    __syncthreads();
    for (int off = 1; off < NSB_MAX; off <<= 1) {
        int a = (tid < NSB_MAX && tid >= off) ? lexcl[tid - off] : 0;
        __syncthreads();
        if (tid < NSB_MAX) lexcl[tid] += a;
        __syncthreads();
    }
    if (tid < NSB_MAX) { lexcl[tid] -= hv; lcur[tid] = lexcl[tid]; }
    __syncthreads();
    #pragma unroll 8
    for (int it = 0; it < T_TILE / 512; ++it) {
        int e = base + it * 512 + tid;
        if (e < E) {
            unsigned d = (unsigned)dst[e];
            unsigned s = (unsigned)src[e];
            int pos = atomicAdd(&lcur[d >> SBB], 1);
            lpk[pos] = (d & 4095u) | (s << SBB);
        }
    }
    __syncthreads();
    for (int b = 0; b < SB; ++b) {
        int lo = lexcl[b], cntb = lhist[b], gb = basec[b];
        for (int t2 = tid; t2 < cntb; t2 += 512)
            pk1[gb + t2] = lpk[lo + t2];
    }
}

// ---- pass 2: per-region counting sort by src-superbucket -> pk2 + tb,
//      degrees -> dinv + z1 (half2) ----
__global__ void __launch_bounds__(1024)
buildpush(const int* __restrict__ bases1, const unsigned* __restrict__ pk1,
          const float* __restrict__ x, float* __restrict__ dinv,
          unsigned* __restrict__ z1h, unsigned* __restrict__ pk2,
          int* __restrict__ tb, int N) {
    __shared__ int deg[4096];         // 16KB: per-dst-node degree
    __shared__ int hist[16][NSB_MAX]; // 8KB: wave-replicated srcSB histogram
    __shared__ int cnt[NSB_MAX];
    __shared__ int cur[NSB_MAX];
    int reg = blockIdx.x, tid = threadIdx.x;
    int ebeg = bases1[reg], eend = bases1[reg + 1];
    int n = eend - ebeg;
    int w = tid >> 6;  // wave id 0..15
    for (int i = tid; i < 4096; i += 1024) deg[i] = 0;
    for (int i = tid; i < 16 * NSB_MAX; i += 1024) ((int*)hist)[i] = 0;
    __syncthreads();
    // pass A: degree + srcSB histogram
    for (int k = tid; k < n; k += 1024) {
        unsigned p = pk1[ebeg + k];
        atomicAdd(&deg[p & 4095u], 1);
        atomicAdd(&hist[w][p >> 24], 1);
    }
    __syncthreads();
    // reduce wave hists
    if (tid < NSB_MAX) {
        int s = 0;
        #pragma unroll
        for (int r = 0; r < 16; ++r) s += hist[r][tid];
        cnt[tid] = s;
        cur[tid] = s;
    }
    __syncthreads();
    // inclusive scan over 128
    for (int off = 1; off < NSB_MAX; off <<= 1) {
        int a = (tid < NSB_MAX && tid >= off) ? cur[tid - off] : 0;
        __syncthreads();
        if (tid < NSB_MAX) cur[tid] += a;
        __syncthreads();
    }
    if (tid < NSB_MAX) {
        int excl = cur[tid] - cnt[tid];
        tb[reg * 129 + tid] = ebeg + excl;
        cur[tid] = excl;
    }
    if (tid == 0) tb[reg * 129 + 128] = eend;
    // node outputs: dinv + z1
    int node0 = reg << SBB;
    for (int t = tid; t < 4096; t += 1024) {
        int i = node0 + t;
        if (i < N) {
            float di = rsqrtf((float)deg[t] + 1.0f);
            dinv[i] = di;
            float2 xv = ((const float2*)x)[i];
            __half2 hz = __floats2half2_rn(xv.x * di, xv.y * di);
            z1h[i] = *(unsigned*)&hz;
        }
    }
    __syncthreads();
    // pass B: place into pk2 ordered by srcSB (writes land in L2-resident
    // 560KB region window; full lines eventually dirty -> clean write-back)
    for (int k = tid; k < n; k += 1024) {
        unsigned p = pk1[ebeg + k];
        int pos = atomicAdd(&cur[p >> 24], 1);
        pk2[ebeg + pos] = p;
    }
}

// ---------------- push kernels ----------------
// block = (region, src-quarter). acc[dst] in LDS; gathers L1-window-resident.

__global__ void __launch_bounds__(512)
push_f2(const unsigned* __restrict__ pk2, const int* __restrict__ tb,
        const unsigned* __restrict__ zt, float* __restrict__ partial) {
    __shared__ float acc[8192];  // 4096 nodes x 2 feats, 32KB
    int bx = blockIdx.x, tid = threadIdx.x;
    int reg = bx >> 2, s = bx & 3;
    for (int i = tid; i < 8192; i += 512) acc[i] = 0.f;
    __syncthreads();
    int e0 = tb[reg * 129 + 32 * s];
    int e1 = tb[reg * 129 + 32 * (s + 1)];
    int k = e0;
    for (; k + 2048 <= e1; k += 2048) {
        unsigned p[4];
        #pragma unroll
        for (int u = 0; u < 4; ++u) p[u] = __builtin_nontemporal_load(&pk2[k + tid + u * 512]);
        unsigned zr[4];
        #pragma unroll
        for (int u = 0; u < 4; ++u) zr[u] = zt[p[u] >> SBB];
        #pragma unroll
        for (int u = 0; u < 4; ++u) {
            float2 v = __half22float2(*(__half2*)&zr[u]);
            unsigned d = (p[u] & 4095u) << 1;
            atomicAdd(&acc[d], v.x);
            atomicAdd(&acc[d + 1], v.y);
        }
    }
    for (int kk = k + tid; kk < e1; kk += 512) {
        unsigned p = pk2[kk];
        unsigned zr = zt[p >> SBB];
        float2 v = __half22float2(*(__half2*)&zr);
        unsigned d = (p & 4095u) << 1;
        atomicAdd(&acc[d], v.x);
        atomicAdd(&acc[d + 1], v.y);
    }
    __syncthreads();
    float* pout = partial + (size_t)bx * 8192;
    for (int i = tid; i < 8192; i += 512) pout[i] = acc[i];
}

__global__ void __launch_bounds__(512)
push_f4(const unsigned* __restrict__ pk2, const int* __restrict__ tb,
        const unsigned long long* __restrict__ zt, float* __restrict__ partial) {
    __shared__ float acc[16384];  // 4096 nodes x 4 feats, 64KB
    int bx = blockIdx.x, tid = threadIdx.x;
    int reg = bx >> 2, s = bx & 3;
    for (int i = tid; i < 16384; i += 512) acc[i] = 0.f;
    __syncthreads();
    int e0 = tb[reg * 129 + 32 * s];
    int e1 = tb[reg * 129 + 32 * (s + 1)];
    int k = e0;
    for (; k + 2048 <= e1; k += 2048) {
        unsigned p[4];
        #pragma unroll
        for (int u = 0; u < 4; ++u) p[u] = __builtin_nontemporal_load(&pk2[k + tid + u * 512]);
        unsigned long long zr[4];
        #pragma unroll
        for (int u = 0; u < 4; ++u) zr[u] = zt[p[u] >> SBB];
        #pragma unroll
        for (int u = 0; u < 4; ++u) {
            unsigned lo = (unsigned)zr[u], hi = (unsigned)(zr[u] >> 32);
            float2 f01 = __half22float2(*(__half2*)&lo);
            float2 f23 = __half22float2(*(__half2*)&hi);
            unsigned d = (p[u] & 4095u) << 2;
            atomicAdd(&acc[d], f01.x);
            atomicAdd(&acc[d + 1], f01.y);
            atomicAdd(&acc[d + 2], f23.x);
            atomicAdd(&acc[d + 3], f23.y);
        }
    }
    for (int kk = k + tid; kk < e1; kk += 512) {
        unsigned p = pk2[kk];
        unsigned long long zr = zt[p >> SBB];
        unsigned lo = (unsigned)zr, hi = (unsigned)(zr >> 32);
        float2 f01 = __half22float2(*(__half2*)&lo);
        float2 f23 = __half22float2(*(__half2*)&hi);
        unsigned d = (p & 4095u) << 2;
        atomicAdd(&acc[d], f01.x);
        atomicAdd(&acc[d + 1], f01.y);
        atomicAdd(&acc[d + 2], f23.x);
        atomicAdd(&acc[d + 3], f23.y);
    }
    __syncthreads();
    float* pout = partial + (size_t)bx * 16384;
    for (int i = tid; i < 16384; i += 512) pout[i] = acc[i];
}

// ---------------- finalize kernels (merge partials + epilogue) ----------------

__global__ void fin1(const float* __restrict__ partial, const unsigned* __restrict__ z1h,
                     const float* __restrict__ dinv, const float* __restrict__ W1,
                     const float* __restrict__ b1, unsigned long long* __restrict__ z2h,
                     int N) {
    int i = blockIdx.x * blockDim.x + threadIdx.x;
    if (i >= N) return;
    int reg = i >> SBB, t = i & 4095;
    float a0, a1;
    {
        unsigned zr = z1h[i];
        float2 z = __half22float2(*(__half2*)&zr);
        a0 = z.x; a1 = z.y;
    }
    #pragma unroll
    for (int s = 0; s < 4; ++s) {
        size_t b = ((size_t)(reg * 4 + s) * 4096 + t) * 2;
        a0 += partial[b];
        a1 += partial[b + 1];
    }
    float di = dinv[i];
    float g0 = di * a0, g1 = di * a1;
    float o0 = di * tanhf(fmaf(g0, W1[0], fmaf(g1, W1[4], b1[0])));
    float o1 = di * tanhf(fmaf(g0, W1[1], fmaf(g1, W1[5], b1[1])));
    float o2 = di * tanhf(fmaf(g0, W1[2], fmaf(g1, W1[6], b1[2])));
    float o3 = di * tanhf(fmaf(g0, W1[3], fmaf(g1, W1[7], b1[3])));
    __half2 ha = __floats2half2_rn(o0, o1);
    __half2 hb = __floats2half2_rn(o2, o3);
    unsigned long long pk = (unsigned long long)(*(unsigned*)&ha) |
                            ((unsigned long long)(*(unsigned*)&hb) << 32);
    z2h[i] = pk;
}

__global__ void fin2(const float* __restrict__ partial,
                     const unsigned long long* __restrict__ z2h,
                     const float* __restrict__ dinv, const float* __restrict__ W2,
                     const float* __restrict__ b2, const float* __restrict__ W3,
                     unsigned* __restrict__ z3h, int N) {
    int i = blockIdx.x * blockDim.x + threadIdx.x;
    if (i >= N) return;
    int reg = i >> SBB, t = i & 4095;
    float a0, a1, a2, a3;
    {
        unsigned long long zr = z2h[i];
        unsigned lo = (unsigned)zr, hi = (unsigned)(zr >> 32);
        float2 f01 = __half22float2(*(__half2*)&lo);
        float2 f23 = __half22float2(*(__half2*)&hi);
        a0 = f01.x; a1 = f01.y; a2 = f23.x; a3 = f23.y;
    }
    #pragma unroll
    for (int s = 0; s < 4; ++s) {
        size_t b = ((size_t)(reg * 4 + s) * 4096 + t) * 4;
        a0 += partial[b];
        a1 += partial[b + 1];
        a2 += partial[b + 2];
        a3 += partial[b + 3];
    }
    float di = dinv[i];
    float g0 = di * a0, g1 = di * a1, g2 = di * a2, g3 = di * a3;
    float h[4];
    #pragma unroll
    for (int c = 0; c < 4; ++c)
        h[c] = tanhf(b2[c] + g0 * W2[c] + g1 * W2[4 + c] + g2 * W2[8 + c] + g3 * W2[12 + c]);
    float v0 = h[0] * W3[0] + h[1] * W3[2] + h[2] * W3[4] + h[3] * W3[6];
    float v1 = h[0] * W3[1] + h[1] * W3[3] + h[2] * W3[5] + h[3] * W3[7];
    __half2 hz = __floats2half2_rn(v0 * di, v1 * di);
    z3h[i] = *(unsigned*)&hz;
}

__global__ void fin3(const float* __restrict__ partial, const unsigned* __restrict__ z3h,
                     const float* __restrict__ dinv, const float* __restrict__ b3,
                     float* __restrict__ out, int N) {
    int i = blockIdx.x * blockDim.x + threadIdx.x;
    if (i >= N) return;
    int reg = i >> SBB, t = i & 4095;
    float a0, a1;
    {
        unsigned zr = z3h[i];
        float2 z = __half22float2(*(__half2*)&zr);
        a0 = z.x; a1 = z.y;
    }
    #pragma unroll
    for (int s = 0; s < 4; ++s) {
        size_t b = ((size_t)(reg * 4 + s) * 4096 + t) * 2;
        a0 += partial[b];
        a1 += partial[b + 1];
    }
    float di = dinv[i];
    ((float2*)out)[i] = make_float2(fmaf(di, a0, b3[0]), fmaf(di, a1, b3[1]));
}

extern "C" void kernel_launch(void* const* d_in, const int* in_sizes, int n_in,
                              void* d_out, int out_size, void* d_ws, size_t ws_size,
                              hipStream_t stream) {
    const float* x  = (const float*)d_in[0];
    const int*   ei = (const int*)d_in[1];
    const float* W1 = (const float*)d_in[2];
    const float* b1 = (const float*)d_in[3];
    const float* W2 = (const float*)d_in[4];
    const float* b2 = (const float*)d_in[5];
    const float* W3 = (const float*)d_in[6];
    const float* b3 = (const float*)d_in[7];
    float* out = (float*)d_out;

    const int N = in_sizes[0] / 2;
    const int E = in_sizes[1] / 2;
    const int* src = ei;
    const int* dst = ei + E;

    const int SB  = (N + (1 << SBB) - 1) >> SBB;     // 123 superbuckets
    const int ntB = (E + T_TILE - 1) / T_TILE;       // 977 tiles of 16K edges
    const int mlen = SB * ntB;                       // ~120K
    const int NB = (mlen + 1023) / 1024;             // ~118

    // ws layout (256B-aligned)
    auto align = [](size_t o) { return (o + 255) & ~(size_t)255; };
    char* wbase = (char*)d_ws;
    size_t off = 0;
    float*    dinv   = (float*)(wbase + off);    off = align(off + (size_t)N * 4);
    unsigned* z1h    = (unsigned*)(wbase + off); off = align(off + (size_t)N * 4);
    unsigned long long* z2h = (unsigned long long*)(wbase + off);
    off = align(off + (size_t)N * 8);
    unsigned* z3h    = (unsigned*)(wbase + off); off = align(off + (size_t)N * 4);
    int*      tb     = (int*)(wbase + off);      off = align(off + (size_t)SB * 129 * 4);
    int*      bsum   = (int*)(wbase + off);      off = align(off + (size_t)1024 * 4);
    int*      bases1 = (int*)(wbase + off);      off = align(off + (size_t)(SB + 1) * 4);
    int*      cnt1   = (int*)(wbase + off);      off = align(off + (size_t)mlen * 4);
    unsigned* pk1    = (unsigned*)(wbase + off); off = align(off + (size_t)E * 4);
    unsigned* pk2    = (unsigned*)(wbase + off); off = align(off + (size_t)E * 4);
    // partial[4 splits][region 4096 nodes][<=4 feats] fp32 = 32.25MB max;
    // aliases pk1 (dead after buildpush).
    float* partial = (float*)pk1;

    dim3 gN((N + TPB - 1) / TPB);
    count1<<<dim3(ntB), dim3(512), 0, stream>>>(dst, cnt1, ntB, E, SB);
    scan_k1<<<dim3(NB), dim3(TPB), 0, stream>>>(cnt1, bsum, mlen);
    scan_k2<<<dim3(1), dim3(1024), 0, stream>>>(bsum, NB);
    scan_k3<<<dim3(NB), dim3(TPB), 0, stream>>>(cnt1, bsum, mlen);
    bases_fix<<<dim3(1), dim3(256), 0, stream>>>(cnt1, ntB, SB, bases1, E);
    scatter1<<<dim3(ntB), dim3(512), 0, stream>>>(dst, src, cnt1, pk1, ntB, E, SB);
    buildpush<<<dim3(SB), dim3(1024), 0, stream>>>(bases1, pk1, x, dinv, z1h, pk2, tb, N);

    push_f2<<<dim3(SB * 4), dim3(512), 0, stream>>>(pk2, tb, z1h, partial);
    fin1<<<gN, dim3(TPB), 0, stream>>>(partial, z1h, dinv, W1, b1, z2h, N);
    push_f4<<<dim3(SB * 4), dim3(512), 0, stream>>>(pk2, tb, z2h, partial);
    fin2<<<gN, dim3(TPB), 0, stream>>>(partial, z2h, dinv, W2, b2, W3, z3h, N);
    push_f2<<<dim3(SB * 4), dim3(512), 0, stream>>>(pk2, tb, z3h, partial);
    fin3<<<gN, dim3(TPB), 0, stream>>>(partial, z3h, dinv, b3, out, N);
}